// Round 10
// baseline (625.405 us; speedup 1.0000x reference)
//
#include <hip/hip_runtime.h>

#define HH 512
#define WW 512
#define NB 8
#define TH 32
#define TW 64
#define ST 80      // LDS row stride in floats (16B-aligned rows)
#define RB 48      // LDS rows per buffer
#define RO 8       // buffer row 8  <-> tile row r0
#define CO 8       // buffer col 8  <-> tile col c0

__device__ __forceinline__ float rcp_f(float x)  { return __builtin_amdgcn_rcpf(x); }
__device__ __forceinline__ float log2_f(float x) { return __builtin_amdgcn_logf(x); }
__device__ __forceinline__ float exp2_f(float x) { return __builtin_amdgcn_exp2f(x); }

#define C1      0.034657359027997264f   /* EPS*ln2       */
#define LOG2_9  3.1699250014423126f
#define NEG_INV -28.853900817779268f    /* -1/(EPS*ln2)  */

__device__ __forceinline__ float4 ld4(const float* p) { return *(const float4*)p; }
__device__ __forceinline__ void   st4(float* p, float4 v) { *(float4*)p = v; }
__device__ __forceinline__ float clamp01(float x) { return fminf(fmaxf(x, 0.0f), 1.0f); }

// One fused soft-morphology step, 2 phases / 2 barriers.
//   Phase AB (erode): OUT = boxavg3x3(IN) over rows [8-B_,40+B_) x cols
//     covering [8-B_,72+B_), fully vectorized (3 b128 + 6 b32 reads, 1 b128
//     write per 4 outputs; h-sums recomputed per row — no intermediate).
//     Edge blocks: per-element clamped recompute (reads only IN -> no extra
//     sync) for groups touching out-of-image; interior groups of border
//     blocks are always fully in-image so the u_out global store stays in
//     the vector path.
//   Phase CD (dilate+skel): per interior group read OUT rows tr-1..tr+1,
//     rcp, h+v sums, log, clip; e from IN (or img); accumulate sk in regs.
template<int B_, bool LAST, bool E_IMG, bool WRITEU>
__device__ __forceinline__ void one_step(
    const float* __restrict__ IN, float* __restrict__ OUT,
    int r0, int c0, int tid, bool edge,
    float* __restrict__ uog, const float* __restrict__ imgb, float4 (&sk)[2])
{
    constexpr int BC0 = ((8 - B_) >> 2) << 2;         // first aligned col-group
    constexpr int LG  = ((71 + B_) >> 2) << 2;        // last col-group
    constexpr int NG  = (LG - BC0) / 4 + 1;
    constexpr int RB0 = RO - B_;
    constexpr int NRB = TH + 2 * B_;

    // ---- phase AB: erode IN -> OUT ----
    for (int gi = tid; gi < NRB * NG; gi += 256) {
        int rr = gi / NG;
        int bc = BC0 + (gi - rr * NG) * 4;
        int r  = RB0 + rr;
        int gr = r0 + r - RO, gc0 = c0 + bc - CO;
        bool vec = !edge || ((unsigned)gr < HH && (unsigned)gc0 <= (WW - 4));
        if (vec) {
            const float* p0 = IN + (r - 1) * ST;
            const float* p1 = IN + r * ST;
            const float* p2 = IN + (r + 1) * ST;
            float4 a = ld4(p0 + bc), b = ld4(p1 + bc), c4 = ld4(p2 + bc);
            float  m = p0[bc - 1] + p1[bc - 1] + p2[bc - 1];
            float  p = p0[bc + 4] + p1[bc + 4] + p2[bc + 4];
            float4 cv;
            cv.x = a.x + b.x + c4.x; cv.y = a.y + b.y + c4.y;
            cv.z = a.z + b.z + c4.z; cv.w = a.w + b.w + c4.w;
            float4 u;
            u.x = (m    + cv.x + cv.y) * (1.0f / 9.0f);
            u.y = (cv.x + cv.y + cv.z) * (1.0f / 9.0f);
            u.z = (cv.y + cv.z + cv.w) * (1.0f / 9.0f);
            u.w = (cv.z + cv.w + p)    * (1.0f / 9.0f);
            st4(OUT + r * ST + bc, u);
            if constexpr (LAST && WRITEU) {
                if (r >= RO && r < RO + TH && bc >= CO && bc < CO + TW)
                    st4(uog + (size_t)gr * WW + gc0, u);
            }
        } else {
            // clamped recompute at the replicate position; reads only IN
            int rcl = min(max(gr, 0), HH - 1) - r0 + RO;
            #pragma unroll
            for (int k = 0; k < 4; ++k) {
                int gc = gc0 + k;
                int ccl = min(max(gc, 0), WW - 1) - c0 + CO;
                const float* q = IN + (rcl - 1) * ST + ccl;
                float u = (q[-1] + q[0] + q[1] +
                           q[ST - 1] + q[ST] + q[ST + 1] +
                           q[2 * ST - 1] + q[2 * ST] + q[2 * ST + 1]) * (1.0f / 9.0f);
                OUT[r * ST + bc + k] = u;
            }
        }
    }
    __syncthreads();

    // ---- phase CD: dilate OUT, skel accumulate ----
    #pragma unroll
    for (int j = 0; j < 2; ++j) {
        int gi = j * 256 + tid;
        int tr = RO + (gi >> 4), bc = CO + (gi & 15) * 4;
        const float* q0 = OUT + (tr - 1) * ST;
        const float* q1 = OUT + tr * ST;
        const float* q2 = OUT + (tr + 1) * ST;
        float4 a = ld4(q0 + bc), b = ld4(q1 + bc), c4 = ld4(q2 + bc);
        float4 vs;
        vs.x = rcp_f(a.x) + rcp_f(b.x) + rcp_f(c4.x);
        vs.y = rcp_f(a.y) + rcp_f(b.y) + rcp_f(c4.y);
        vs.z = rcp_f(a.z) + rcp_f(b.z) + rcp_f(c4.z);
        vs.w = rcp_f(a.w) + rcp_f(b.w) + rcp_f(c4.w);
        float vm = rcp_f(q0[bc - 1]) + rcp_f(q1[bc - 1]) + rcp_f(q2[bc - 1]);
        float vp = rcp_f(q0[bc + 4]) + rcp_f(q1[bc + 4]) + rcp_f(q2[bc + 4]);
        float4 d;
        d.x = clamp01(C1 * (log2_f(vm   + vs.x + vs.y) - LOG2_9));
        d.y = clamp01(C1 * (log2_f(vs.x + vs.y + vs.z) - LOG2_9));
        d.z = clamp01(C1 * (log2_f(vs.y + vs.z + vs.w) - LOG2_9));
        d.w = clamp01(C1 * (log2_f(vs.z + vs.w + vp)   - LOG2_9));
        float4 ee;
        if constexpr (E_IMG) {
            ee = ld4(imgb + (size_t)(r0 + tr - RO) * WW + (c0 + bc - CO));
        } else {
            float4 u = ld4(IN + tr * ST + bc);
            ee.x = -C1 * log2_f(u.x); ee.y = -C1 * log2_f(u.y);
            ee.z = -C1 * log2_f(u.z); ee.w = -C1 * log2_f(u.w);
        }
        sk[j].x += fmaxf(ee.x - d.x, 0.0f);
        sk[j].y += fmaxf(ee.y - d.y, 0.0f);
        sk[j].z += fmaxf(ee.z - d.z, 0.0f);
        sk[j].w += fmaxf(ee.w - d.w, 0.0f);
    }
    __syncthreads();   // protects IN (e-reads) before next step overwrites it
}

template<int B_, int REMAIN, bool E_IMG, bool WRITEU>
struct Chain {
    static __device__ __forceinline__ void run(
        float* IN, float* OUT, int r0, int c0, int tid, bool edge,
        float* uog, const float* imgb, float4 (&sk)[2])
    {
        one_step<B_, (REMAIN == 1), E_IMG, WRITEU>(IN, OUT, r0, c0, tid, edge, uog, imgb, sk);
        if constexpr (REMAIN > 1)
            Chain<B_ - 1, REMAIN - 1, false, WRITEU>::run(OUT, IN, r0, c0, tid, edge, uog, imgb, sk);
    }
};

template<bool FIRST, int NSTEP, bool WRITEU>
__global__ __launch_bounds__(256)   // no min-waves clamp: (256,5) forced spills (r8)
void sk_fused(const float* __restrict__ u_in, const float* __restrict__ img,
              float* __restrict__ u_out, float* __restrict__ skel)
{
    constexpr int A0 = NSTEP + 1;
    __shared__ __align__(16) float P[RB * ST];   // 15.0 KB
    __shared__ __align__(16) float Q[RB * ST];   // 15.0 KB (30 KB -> 5 blk/CU by LDS)

    const int r0  = blockIdx.y * TH;
    const int c0  = blockIdx.x * TW;
    const int tid = threadIdx.x;
    const bool edge = (blockIdx.x == 0) | (blockIdx.x == gridDim.x - 1) |
                      (blockIdx.y == 0) | (blockIdx.y == gridDim.y - 1);
    const size_t boff = (size_t)blockIdx.z * (HH * WW);
    const float* imgb = img + boff;
    float* uog = u_out + boff;
    float* skb = skel + boff;

    // stage u_k at halo A0, clamped replicate
    {
        constexpr int SH = TH + 2 * A0, SW = TW + 2 * A0;
        const float* uin = u_in + boff;
        for (int i = tid; i < SH * SW; i += 256) {
            int rr = i / SW, cc = i - rr * SW;
            int gr = min(max(r0 + rr - A0, 0), HH - 1);
            int gc = min(max(c0 + cc - A0, 0), WW - 1);
            float v;
            if constexpr (FIRST) v = exp2_f(imgb[gr * WW + gc] * NEG_INV);
            else                 v = uin[gr * WW + gc];
            P[(RO - A0 + rr) * ST + (CO - A0 + cc)] = v;
        }
    }
    __syncthreads();

    float4 sk[2];
    sk[0] = make_float4(0.f, 0.f, 0.f, 0.f);
    sk[1] = make_float4(0.f, 0.f, 0.f, 0.f);

    Chain<NSTEP, NSTEP, FIRST, WRITEU>::run(P, Q, r0, c0, tid, edge, uog, imgb, sk);

    #pragma unroll
    for (int j = 0; j < 2; ++j) {
        int gi = j * 256 + tid;
        int tr = RO + (gi >> 4), bc = CO + (gi & 15) * 4;
        float* sp = skb + (size_t)(r0 + tr - RO) * WW + (c0 + bc - CO);
        if constexpr (FIRST) {
            *(float4*)sp = sk[j];
        } else {
            float4 old = *(const float4*)sp;
            old.x += sk[j].x; old.y += sk[j].y; old.z += sk[j].z; old.w += sk[j].w;
            *(float4*)sp = old;
        }
    }
}

extern "C" void kernel_launch(void* const* d_in, const int* in_sizes, int n_in,
                              void* d_out, int out_size, void* d_ws, size_t ws_size,
                              hipStream_t stream) {
    const float* img = (const float*)d_in[0];
    float* skel = (float*)d_out;
    const size_t N = (size_t)NB * HH * WW;
    float* ua = (float*)d_ws;
    float* ub = ua + N;                       // 16.8 MB of ws used

    dim3 grid(WW / TW, HH / TH, NB);          // (8,16,8) = 1024 blocks

    // steps 0..4 (e_0 = img exactly), writes u5
    sk_fused<true, 5, true><<<grid, 256, 0, stream>>>(nullptr, img, ua, skel);

    // steps 5..49 in 9 kernels of 5
    float* uin = ua; float* uout = ub;
    for (int t = 0; t < 9; ++t) {
        sk_fused<false, 5, true><<<grid, 256, 0, stream>>>(uin, img, uout, skel);
        float* tmp = uin; uin = uout; uout = tmp;
    }

    // step 50 (no u write needed)
    sk_fused<false, 1, false><<<grid, 256, 0, stream>>>(uin, img, uout, skel);
}

// Round 13
// 444.233 us; speedup vs baseline: 1.4078x; 1.4078x over previous
//
#include <hip/hip_runtime.h>

#define HH 512
#define WW 512
#define NB 8
#define TH 32
#define TW 64
#define ST 84      // LDS row stride in floats; 84%32=20 banks/row offset breaks
                   // the ST=80 row-pair bank collision (r9: 4.6M, r10: 12.4M cyc)
#define RB 48      // LDS rows per buffer
#define RO 8       // buffer row 8  <-> tile row r0
#define CO 8       // buffer col 8  <-> tile col c0

__device__ __forceinline__ float rcp_f(float x)  { return __builtin_amdgcn_rcpf(x); }
__device__ __forceinline__ float log2_f(float x) { return __builtin_amdgcn_logf(x); }
__device__ __forceinline__ float exp2_f(float x) { return __builtin_amdgcn_exp2f(x); }

#define C1      0.034657359027997264f   /* EPS*ln2       */
#define LOG2_9  3.1699250014423126f
#define NEG_INV -28.853900817779268f    /* -1/(EPS*ln2)  */

__device__ __forceinline__ float4 ld4(const float* p) { return *(const float4*)p; }
__device__ __forceinline__ void   st4(float* p, float4 v) { *(float4*)p = v; }
__device__ __forceinline__ float clamp01(float x) { return fminf(fmaxf(x, 0.0f), 1.0f); }

// One fused step, 4 phases (r9 structure — r10's 2-phase merge regressed:
// +50% LDS reads, 3x bank conflicts). P holds u_k on entry, u_{k+1} on exit.
// Q is scratch (h-sums, then rcp-h-sums). Out-of-image halo entries are
// computed AT the clamped position so replicate-pad stays exact recursively.
template<int B_, bool LAST, bool E_IMG, bool WRITEU>
__device__ __forceinline__ void one_step(
    float* __restrict__ P, float* __restrict__ Q,
    int r0, int c0, int tid, bool edge,
    float* __restrict__ uog, const float* __restrict__ imgb,
    float4 (&sk)[2])
{
    constexpr int BC0 = ((8 - B_) >> 2) << 2;         // first col-group (cols needed: [8-B_, 72+B_))
    constexpr int BCL = ((71 + B_) >> 2) << 2;        // last col-group
    constexpr int NG  = (BCL - BC0) / 4 + 1;
    constexpr int RA0 = RO - 1 - B_;                  // phase A rows [RA0, RA0+NRA)
    constexpr int NRA = TH + 2 + 2 * B_;
    constexpr int RB0 = RO - B_;                      // phase B rows [RB0, RB0+NRB)
    constexpr int NRB = TH + 2 * B_;

    // hoist e = -C1*log2(u_k) before P is overwritten in phase B
    float4 e[2];
    if constexpr (!E_IMG) {
        #pragma unroll
        for (int j = 0; j < 2; ++j) {
            int gi = j * 256 + tid;
            int tr = RO + (gi >> 4), bc = CO + (gi & 15) * 4;
            float4 u = ld4(P + tr * ST + bc);
            e[j].x = -C1 * log2_f(u.x); e[j].y = -C1 * log2_f(u.y);
            e[j].z = -C1 * log2_f(u.z); e[j].w = -C1 * log2_f(u.w);
        }
    }

    // phase A: Q[r][c] = P[r][c-1]+P[r][c]+P[r][c+1]  (centered h-sums)
    for (int gi = tid; gi < NRA * NG; gi += 256) {
        int rr = gi / NG;
        int bc = BC0 + (gi - rr * NG) * 4;
        const float* row = P + (RA0 + rr) * ST;
        float4 q = ld4(row + bc);
        float pm1 = row[bc > 0 ? bc - 1 : 0];
        float p4  = row[bc + 4];
        float4 o;
        o.x = pm1 + q.x + q.y; o.y = q.x + q.y + q.z;
        o.z = q.y + q.z + q.w; o.w = q.z + q.w + p4;
        st4(Q + (RA0 + rr) * ST + bc, o);
    }
    __syncthreads();

    // phase B: P[r][c] = (Q[r-1][c]+Q[r][c]+Q[r+1][c]) / 9   (u_{k+1})
    // vector path for every fully-in-image group (incl. edge blocks);
    // scalar clamped recompute only for groups touching out-of-image.
    for (int gi = tid; gi < NRB * NG; gi += 256) {
        int rr = gi / NG;
        int bc = BC0 + (gi - rr * NG) * 4;
        int r  = RB0 + rr;
        int gr = r0 + r - RO, gc0 = c0 + bc - CO;
        bool vec = !edge || ((unsigned)gr < HH && (unsigned)gc0 <= (WW - 4));
        if (vec) {
            const float* h = Q + (r - 1) * ST + bc;
            float4 t = ld4(h), m = ld4(h + ST), b = ld4(h + 2 * ST);
            float4 u;
            u.x = (t.x + m.x + b.x) * (1.0f / 9.0f);
            u.y = (t.y + m.y + b.y) * (1.0f / 9.0f);
            u.z = (t.z + m.z + b.z) * (1.0f / 9.0f);
            u.w = (t.w + m.w + b.w) * (1.0f / 9.0f);
            st4(P + r * ST + bc, u);
            if constexpr (LAST && WRITEU) {
                if (r >= RO && r < RO + TH && bc >= CO && bc < CO + TW)
                    st4(uog + (size_t)gr * WW + gc0, u);
            }
        } else {
            #pragma unroll
            for (int k = 0; k < 4; ++k) {
                int gc = gc0 + k;
                int rcl = min(max(gr, 0), HH - 1) - r0 + RO;
                int ccl = min(max(gc, 0), WW - 1) - c0 + CO;
                float u = (Q[(rcl - 1) * ST + ccl] + Q[rcl * ST + ccl] +
                           Q[(rcl + 1) * ST + ccl]) * (1.0f / 9.0f);
                P[r * ST + bc + k] = u;
            }
        }
    }
    __syncthreads();

    // phase C: Q[r][c] = rcp(P[r][c-1])+rcp(P[r][c])+rcp(P[r][c+1]),
    //          rows [RO-1, RO+TH+1), cols [CO, CO+TW)
    for (int gi = tid; gi < (TH + 2) * 16; gi += 256) {
        int rr = gi >> 4;
        int bc = CO + (gi & 15) * 4;
        const float* row = P + (RO - 1 + rr) * ST;
        float4 q = ld4(row + bc);
        float pm1 = row[bc - 1], p4 = row[bc + 4];
        float a0 = rcp_f(pm1), a1 = rcp_f(q.x), a2 = rcp_f(q.y),
              a3 = rcp_f(q.z), a4 = rcp_f(q.w), a5 = rcp_f(p4);
        float4 o;
        o.x = a0 + a1 + a2; o.y = a1 + a2 + a3;
        o.z = a2 + a3 + a4; o.w = a3 + a4 + a5;
        st4(Q + (RO - 1 + rr) * ST + bc, o);
    }
    __syncthreads();

    // phase D: dilate v-sum, log, clip, skel accumulate
    #pragma unroll
    for (int j = 0; j < 2; ++j) {
        int gi = j * 256 + tid;
        int tr = RO + (gi >> 4), bc = CO + (gi & 15) * 4;
        const float* h = Q + (tr - 1) * ST + bc;
        float4 t = ld4(h), m = ld4(h + ST), b = ld4(h + 2 * ST);
        float4 d;
        d.x = clamp01(C1 * (log2_f(t.x + m.x + b.x) - LOG2_9));
        d.y = clamp01(C1 * (log2_f(t.y + m.y + b.y) - LOG2_9));
        d.z = clamp01(C1 * (log2_f(t.z + m.z + b.z) - LOG2_9));
        d.w = clamp01(C1 * (log2_f(t.w + m.w + b.w) - LOG2_9));
        float4 ee;
        if constexpr (E_IMG)
            ee = ld4(imgb + (size_t)(r0 + tr - RO) * WW + (c0 + bc - CO));
        else
            ee = e[j];
        sk[j].x += fmaxf(ee.x - d.x, 0.0f);
        sk[j].y += fmaxf(ee.y - d.y, 0.0f);
        sk[j].z += fmaxf(ee.z - d.z, 0.0f);
        sk[j].w += fmaxf(ee.w - d.w, 0.0f);
    }
    __syncthreads();
}

template<int B_, int REMAIN, bool E_IMG, bool WRITEU>
struct Chain {
    static __device__ __forceinline__ void run(
        float* P, float* Q, int r0, int c0, int tid, bool edge,
        float* uog, const float* imgb, float4 (&sk)[2])
    {
        one_step<B_, (REMAIN == 1), E_IMG, WRITEU>(P, Q, r0, c0, tid, edge, uog, imgb, sk);
        if constexpr (REMAIN > 1)
            Chain<B_ - 1, REMAIN - 1, false, WRITEU>::run(P, Q, r0, c0, tid, edge, uog, imgb, sk);
    }
};

template<bool FIRST, int NSTEP, bool WRITEU>
__global__ __launch_bounds__(256)   // no min-waves clamp: (256,5) forced spills (r8)
void sk_fused(const float* __restrict__ u_in, const float* __restrict__ img,
              float* __restrict__ u_out, float* __restrict__ skel)
{
    constexpr int A0 = NSTEP + 1;
    __shared__ __align__(16) float P[RB * ST];   // 15.75 KB
    __shared__ __align__(16) float Q[RB * ST];   // 15.75 KB (31.5 KB -> 5 blk/CU by LDS)

    const int r0  = blockIdx.y * TH;
    const int c0  = blockIdx.x * TW;
    const int tid = threadIdx.x;
    const bool edge = (blockIdx.x == 0) | (blockIdx.x == gridDim.x - 1) |
                      (blockIdx.y == 0) | (blockIdx.y == gridDim.y - 1);
    const size_t boff = (size_t)blockIdx.z * (HH * WW);
    const float* imgb = img + boff;
    float* uog = u_out + boff;
    float* skb = skel + boff;

    // stage u_k at halo A0, clamped replicate (A0=8 -> rows [0,48) cols [0,80))
    {
        constexpr int SH = TH + 2 * A0, SW = TW + 2 * A0;
        const float* uin = u_in + boff;
        for (int i = tid; i < SH * SW; i += 256) {
            int rr = i / SW, cc = i - rr * SW;
            int gr = min(max(r0 + rr - A0, 0), HH - 1);
            int gc = min(max(c0 + cc - A0, 0), WW - 1);
            float v;
            if constexpr (FIRST) v = exp2_f(imgb[gr * WW + gc] * NEG_INV);
            else                 v = uin[gr * WW + gc];
            P[(RO - A0 + rr) * ST + (CO - A0 + cc)] = v;
        }
    }
    __syncthreads();

    float4 sk[2];
    sk[0] = make_float4(0.f, 0.f, 0.f, 0.f);
    sk[1] = make_float4(0.f, 0.f, 0.f, 0.f);

    Chain<NSTEP, NSTEP, FIRST, WRITEU>::run(P, Q, r0, c0, tid, edge, uog, imgb, sk);

    #pragma unroll
    for (int j = 0; j < 2; ++j) {
        int gi = j * 256 + tid;
        int tr = RO + (gi >> 4), bc = CO + (gi & 15) * 4;
        float* sp = skb + (size_t)(r0 + tr - RO) * WW + (c0 + bc - CO);
        if constexpr (FIRST) {
            *(float4*)sp = sk[j];
        } else {
            float4 old = *(const float4*)sp;
            old.x += sk[j].x; old.y += sk[j].y; old.z += sk[j].z; old.w += sk[j].w;
            *(float4*)sp = old;
        }
    }
}

extern "C" void kernel_launch(void* const* d_in, const int* in_sizes, int n_in,
                              void* d_out, int out_size, void* d_ws, size_t ws_size,
                              hipStream_t stream) {
    const float* img = (const float*)d_in[0];
    float* skel = (float*)d_out;
    const size_t N = (size_t)NB * HH * WW;
    float* ua = (float*)d_ws;
    float* ub = ua + N;                       // 16.8 MB of ws used

    dim3 grid(WW / TW, HH / TH, NB);          // (8,16,8) = 1024 blocks

    // steps 0..6 (e_0 = img exactly), writes u7
    sk_fused<true, 7, true><<<grid, 256, 0, stream>>>(nullptr, img, ua, skel);

    // steps 7..48 in 6 kernels of 7
    float* uin = ua; float* uout = ub;
    for (int t = 0; t < 6; ++t) {
        sk_fused<false, 7, true><<<grid, 256, 0, stream>>>(uin, img, uout, skel);
        float* tmp = uin; uin = uout; uout = tmp;
    }

    // steps 49..50 (no u write needed)
    sk_fused<false, 2, false><<<grid, 256, 0, stream>>>(uin, img, uout, skel);
}